// Round 12
// baseline (193.585 us; speedup 1.0000x reference)
//
#include <hip/hip_runtime.h>

typedef float  f32x4  __attribute__((ext_vector_type(4)));
typedef int    i32x4  __attribute__((ext_vector_type(4)));
typedef int    i32x8  __attribute__((ext_vector_type(8)));

#define NB 32
#define NC 256
#define NHW 4096                  // 64*64
#define NN (NB*NHW)               // 131072 rows
#define NK 1024                   // codes
#define NUMEL ((size_t)NN*NC)     // 33554432
#define BM 64                     // rows per block
#define NTILES (NN/BM)            // 2048 blocks
#define NCHUNK 16                 // 64 codes per chunk
#define CH_BYTES 16384            // 64 codes * 256 k * 1B
#define ESCALE 512.0f             // emb scaled by 512 before fp8 quant
#define SC1 0x7F7F7F7F            // E8M0 scale = 1.0 in all byte slots

// ---------- prep: prepack emb -> fp8 fragments, enorm2, zero counter ----------
// packed byte off bits: [ch 4][cg 2][h 1][g 2][col 4][kk 5]
// code = ch*64 + cg*16 + col ; k = h*128 + g*32 + kk
__global__ void vq_prep(const float* __restrict__ emb, unsigned char* __restrict__ packed,
                        float* __restrict__ enorm2, int* __restrict__ ctr) {
    const int blk = blockIdx.x;
    const int tid = threadIdx.x;
    if (blk < 256) {
        const int base = (blk * 256 + tid) * 4;   // 4 bytes/thread, same k-quad
        const int kk0 = base & 31;
        const int col = (base >> 5) & 15;
        const int g   = (base >> 9) & 3;
        const int h   = (base >> 11) & 1;
        const int cg  = (base >> 12) & 3;
        const int ch  = base >> 14;
        const int code = ch * 64 + cg * 16 + col;
        const int k    = h * 128 + g * 32 + kk0;
        const float4 v = *(const float4*)(emb + (size_t)code * NC + k);
        int w = 0;
        w = __builtin_amdgcn_cvt_pk_fp8_f32(v.x * ESCALE, v.y * ESCALE, w, false);
        w = __builtin_amdgcn_cvt_pk_fp8_f32(v.z * ESCALE, v.w * ESCALE, w, true);
        *(int*)(packed + base) = w;
    } else {
        const int k = (blk - 256) * 256 + tid;    // 0..1023
        const float4* row = (const float4*)(emb + (size_t)k * NC);
        float s = 0.f;
#pragma unroll
        for (int i = 0; i < NC / 4; ++i) {
            float4 v = row[i];
            s = fmaf(v.x, v.x, fmaf(v.y, v.y, fmaf(v.z, v.z, fmaf(v.w, v.w, s))));
        }
        enorm2[k] = -256.0f * s;                  // = -||e_scaled||^2 / 2
        if (blk == 256 && tid == 0) *ctr = 0;
    }
}

#define MX(A, B, C) __builtin_amdgcn_mfma_scale_f32_16x16x128_f8f6f4((A), (B), (C), 0, 0, 0, SC1, 0, SC1)

#define TAIL(MT, A, CH)                                                              \
    _Pragma("unroll")                                                                \
    for (int q = 0; q < 4; ++q) {                                                    \
        unsigned u = (__builtin_bit_cast(unsigned, (A)[q]) & 0xFFFFFFF0u) | (unsigned)(CH); \
        bestv[MT][q] = fmaxf(bestv[MT][q], __builtin_bit_cast(float, u));            \
    }

// one 64-code chunk. Latency-reordered: next-chunk loads issue right after the
// cluster that last reads the register they overwrite (~240-340 cyc cover, no extra regs)
#define KSTEP(CH, PF) do {                                                           \
    f32x4 a0 = {en, en, en, en}, a1 = a0, a2 = a0, a3 = a0;                          \
    __builtin_amdgcn_s_setprio(1);                                                   \
    a0 = MX(af[0][0], bA, a0); a1 = MX(af[1][0], bA, a1);                            \
    a2 = MX(af[2][0], bA, a2); a3 = MX(af[3][0], bA, a3);                            \
    __builtin_amdgcn_s_setprio(0);                                                   \
    if (PF) { bA = *(const i32x8*)(gpb + ((CH) + 1) * CH_BYTES);                     \
              en = enp[(((CH) + 1) << 6)]; }                                         \
    __builtin_amdgcn_s_setprio(1);                                                   \
    a0 = MX(af[0][1], bB, a0); a1 = MX(af[1][1], bB, a1);                            \
    a2 = MX(af[2][1], bB, a2); a3 = MX(af[3][1], bB, a3);                            \
    __builtin_amdgcn_s_setprio(0);                                                   \
    if (PF) { bB = *(const i32x8*)(gpb + ((CH) + 1) * CH_BYTES + 2048); }            \
    TAIL(0, a0, CH); TAIL(1, a1, CH); TAIL(2, a2, CH); TAIL(3, a3, CH);              \
} while (0)

// ---------- kernel A: distances + argmin (256 thr = 4 cg-waves over same 64 rows) ----------
__global__ __launch_bounds__(256, 4)
void vq_dist(const float* __restrict__ x, const unsigned char* __restrict__ packed,
             const float* __restrict__ enorm2, unsigned short* __restrict__ widx_g,
             float* __restrict__ partials)
{
    __shared__ __align__(16) char LDS[21536];
    char*  Xb   = LDS;                       // [64 r][256 B] fp8 XOR-swz, 16 KiB
    float* enl2 = (float*)(LDS + 16384);     // [1024]
    float* redv = (float*)(LDS + 20480);     // [4][64] packed floats
    float* wsum = (float*)(LDS + 21504);     // [4]

    const int tid  = threadIdx.x;
    const int blk  = blockIdx.x;
    const int b    = blk >> 6;
    const int hw0  = (blk & 63) << 6;
    const int cg   = tid >> 6;                 // wave = 16-code group
    const int lane = tid & 63;
    const int col  = lane & 15;
    const int g    = lane >> 4;

    // ---- stage x -> Xb[r][c] fp8 (scale 1), XOR-swizzled; + sum x^2 (fp32) ----
    float xsq = 0.f;
#pragma unroll
    for (int it = 0; it < 2; ++it) {
        const int r4 = (tid & 15) << 2;
        const int c0 = (((tid >> 4) & 15) + (it << 4)) << 3;
        float4 va[8];
#pragma unroll
        for (int cq = 0; cq < 8; ++cq) {
            va[cq] = *(const float4*)(x + (size_t)(b * NC + c0 + cq) * NHW + hw0 + r4);
            xsq = fmaf(va[cq].x, va[cq].x, fmaf(va[cq].y, va[cq].y,
                  fmaf(va[cq].z, va[cq].z, fmaf(va[cq].w, va[cq].w, xsq))));
        }
#pragma unroll
        for (int q = 0; q < 4; ++q) {
            const int r = r4 + q;
            int w0 = 0, w1 = 0;
            w0 = __builtin_amdgcn_cvt_pk_fp8_f32(((const float*)&va[0])[q], ((const float*)&va[1])[q], w0, false);
            w0 = __builtin_amdgcn_cvt_pk_fp8_f32(((const float*)&va[2])[q], ((const float*)&va[3])[q], w0, true);
            w1 = __builtin_amdgcn_cvt_pk_fp8_f32(((const float*)&va[4])[q], ((const float*)&va[5])[q], w1, false);
            w1 = __builtin_amdgcn_cvt_pk_fp8_f32(((const float*)&va[6])[q], ((const float*)&va[7])[q], w1, true);
            int2 wp = {w0, w1};
            *(int2*)(Xb + r * 256 + (c0 ^ ((r & 15) << 4))) = wp;
        }
    }
    *(float4*)&enl2[tid << 2] = *(const float4*)&enorm2[tid << 2];
#pragma unroll
    for (int o = 32; o > 0; o >>= 1) xsq += __shfl_down(xsq, o, 64);
    if (lane == 0) wsum[cg] = xsq;
    __syncthreads();

    // ---- A fragments: af[mt][h] = rows mt*16+col, k = h*128 + g*32 + (0..31) ----
    i32x8 af[4][2];
#pragma unroll
    for (int mt = 0; mt < 4; ++mt) {
        const int r = (mt << 4) + col;
#pragma unroll
        for (int h = 0; h < 2; ++h) {
            const int off = (h << 7) + (g << 5);
            const i32x4 lo = *(const i32x4*)(Xb + r * 256 + ((off)      ^ (col << 4)));
            const i32x4 hi = *(const i32x4*)(Xb + r * 256 + ((off + 16) ^ (col << 4)));
            af[mt][h] = __builtin_shufflevector(lo, hi, 0, 1, 2, 3, 4, 5, 6, 7);
        }
    }

    float bestv[4][4];
#pragma unroll
    for (int mt = 0; mt < 4; ++mt)
#pragma unroll
        for (int q = 0; q < 4; ++q) bestv[mt][q] = -3.4e38f;   // maximize 512*x.e - 256||e||^2

    // ---- K-loop: K=128 MX MFMA, latency-reordered prefetch, no barriers ----
    const char*  gpb = (const char*)packed + (cg << 12) + (lane << 5);   // 32 B/lane
    const float* enp = enl2 + (cg << 4) + col;
    i32x8 bA, bB;
    bA = *(const i32x8*)(gpb);
    bB = *(const i32x8*)(gpb + 2048);
    float en = enp[0];

#pragma unroll 1
    for (int ch = 0; ch < NCHUNK - 1; ++ch) KSTEP(ch, 1);
    KSTEP(NCHUNK - 1, 0);

    // ---- rebuild 10-bit code id in low mantissa bits ----
#pragma unroll
    for (int mt = 0; mt < 4; ++mt)
#pragma unroll
        for (int q = 0; q < 4; ++q) {
            unsigned u = __builtin_bit_cast(unsigned, bestv[mt][q]);
            const unsigned id = ((u & 15u) << 6) | ((unsigned)cg << 4) | (unsigned)col;
            u = (u & 0xFFFFFC00u) | id;
            bestv[mt][q] = __builtin_bit_cast(float, u);
        }

    // ---- cross-lane argmax over the 16 col-lanes (id travels inside float) ----
#pragma unroll
    for (int m = 1; m <= 8; m <<= 1)
#pragma unroll
        for (int mt = 0; mt < 4; ++mt)
#pragma unroll
            for (int q = 0; q < 4; ++q)
                bestv[mt][q] = fmaxf(bestv[mt][q], __shfl_xor(bestv[mt][q], m, 64));

    // ---- cross-wave (cg) argmax + widx + loss partial ----
    if (col == 0) {
#pragma unroll
        for (int mt = 0; mt < 4; ++mt)
#pragma unroll
            for (int q = 0; q < 4; ++q)
                redv[(cg << 6) + (mt << 4) + (g << 2) + q] = bestv[mt][q];
    }
    __syncthreads();
    if (tid < 64) {
        float w = fmaxf(fmaxf(redv[tid], redv[64 + tid]), fmaxf(redv[128 + tid], redv[192 + tid]));
        const unsigned u = __builtin_bit_cast(unsigned, w);
        widx_g[blk * 64 + tid] = (unsigned short)(u & 1023u);
        // true min-dist part: ||e||^2 - 2 x.e = -val/256
        const float val = __builtin_bit_cast(float, u & 0xFFFFFC00u);
        float bsum = val * (-1.0f / 256.0f);
#pragma unroll
        for (int o = 32; o > 0; o >>= 1) bsum += __shfl_down(bsum, o, 64);
        if (tid == 0)
            partials[blk] = bsum + wsum[0] + wsum[1] + wsum[2] + wsum[3];  // + sum x^2
    }
}

// ---------- kernel B: gather + transposed coalesced write + fused loss-final ----------
__global__ __launch_bounds__(512, 4)
void vq_scatter(const float* __restrict__ emb, const unsigned short* __restrict__ widx_g,
                float* __restrict__ out, const float* __restrict__ partials, int* __restrict__ ctr)
{
    __shared__ __align__(16) char LDS[33540];
    float* Qt   = (float*)LDS;               // [64][130] f32 (c-half), 33280 B
    int*   widx = (int*)(LDS + 33280);       // [64]
    __shared__ int lastflag;

    const int tid  = threadIdx.x;
    const int blk  = blockIdx.x;
    const int b    = blk >> 6;
    const int hw0  = (blk & 63) << 6;
    const int wv   = tid >> 6;
    const int lane = tid & 63;

    if (tid < 64) widx[tid] = (int)widx_g[blk * 64 + tid];
    __syncthreads();

#pragma unroll
    for (int h = 0; h < 2; ++h) {
        // gather: each wave owns 8 rows; reads half an emb row (512 B) coalesced
#pragma unroll
        for (int rr = 0; rr < 8; ++rr) {
            const int r  = (wv << 3) + rr;
            const int ki = widx[r];                         // wave-uniform broadcast
            const float2 ev = *(const float2*)(emb + (size_t)ki * NC + (h << 7) + (lane << 1));
            *(float2*)&Qt[r * 130 + (lane << 1)] = ev;
        }
        __syncthreads();
        // transposed coalesced write: 16 c-columns per wave
#pragma unroll 4
        for (int cc = 0; cc < 16; ++cc) {
            const int cl = (wv << 4) + cc;                  // 0..127 within half
            out[(size_t)(b * NC + (h << 7) + cl) * NHW + hw0 + lane] = Qt[lane * 130 + cl];
        }
        __syncthreads();
    }

    // ---- fused loss-final: last block reduces partials (deterministic order) ----
    if (tid == 0) {
        __threadfence();
        lastflag = (atomicAdd(ctr, 1) == NTILES - 1) ? 1 : 0;
    }
    __syncthreads();
    if (lastflag && tid < 64) {
        __threadfence();
        float s = 0.f;
#pragma unroll 4
        for (int i = tid; i < NTILES; i += 64) s += partials[i];
#pragma unroll
        for (int o = 32; o > 0; o >>= 1) s += __shfl_down(s, o, 64);
        if (tid == 0) out[NUMEL] = 1.25f * s / (float)NUMEL;
    }
}

extern "C" void kernel_launch(void* const* d_in, const int* in_sizes, int n_in,
                              void* d_out, int out_size, void* d_ws, size_t ws_size,
                              hipStream_t stream) {
    const float* x   = (const float*)d_in[0];
    const float* emb = (const float*)d_in[1];
    float* out = (float*)d_out;                              // [NUMEL] quantized + [1] loss
    char*  ws  = (char*)d_ws;
    float* partials = (float*)ws;                            // 2048 floats           @ 0
    int*   ctr      = (int*)(ws + 8192);                     // 1 int                 @ 8K
    float* enorm2   = (float*)(ws + 12288);                  // 1024 floats           @ 12K
    unsigned char*  packed = (unsigned char*)(ws + 16384);   // 256 KiB fp8 packed    @ 16K
    unsigned short* widx   = (unsigned short*)(ws + 278528); // 256 KiB indices

    hipLaunchKernelGGL(vq_prep, dim3(260), dim3(256), 0, stream, emb, packed, enorm2, ctr);
    hipLaunchKernelGGL(vq_dist, dim3(NTILES), dim3(256), 0, stream, x, packed, enorm2, widx, partials);
    hipLaunchKernelGGL(vq_scatter, dim3(NTILES), dim3(512), 0, stream, emb, widx, out, partials, ctr);
}

// Round 13
// 120.986 us; speedup vs baseline: 1.6001x; 1.6001x over previous
//
#include <hip/hip_runtime.h>

typedef float  f32x4  __attribute__((ext_vector_type(4)));
typedef int    i32x4  __attribute__((ext_vector_type(4)));
typedef int    i32x8  __attribute__((ext_vector_type(8)));

#define NB 32
#define NC 256
#define NHW 4096                  // 64*64
#define NN (NB*NHW)               // 131072 rows
#define NK 1024                   // codes
#define NUMEL ((size_t)NN*NC)     // 33554432
#define BM 64                     // rows per block
#define NTILES (NN/BM)            // 2048 blocks
#define NCHUNK 16                 // 64 codes per chunk
#define CH_BYTES 16384            // 64 codes * 256 k * 1B
#define QTS 258                   // Qt row stride (floats)
#define ESCALE 512.0f             // emb scaled by 512 before fp8 quant
#define SC1 0x7F7F7F7F            // E8M0 scale = 1.0 in all byte slots

// ---------- prep: prepack emb -> fp8 fragments + enorm2 (merged) ----------
// packed byte off bits: [ch 4][cg 2][h 1][g 2][col 4][kk 5]
// code = ch*64 + cg*16 + col ; k = h*128 + g*32 + kk
__global__ void vq_prep(const float* __restrict__ emb, unsigned char* __restrict__ packed,
                        float* __restrict__ enorm2) {
    const int blk = blockIdx.x;
    const int tid = threadIdx.x;
    if (blk < 256) {
        const int base = (blk * 256 + tid) * 4;   // 4 bytes/thread, same k-quad
        const int kk0 = base & 31;
        const int col = (base >> 5) & 15;
        const int g   = (base >> 9) & 3;
        const int h   = (base >> 11) & 1;
        const int cg  = (base >> 12) & 3;
        const int ch  = base >> 14;
        const int code = ch * 64 + cg * 16 + col;
        const int k    = h * 128 + g * 32 + kk0;
        const float4 v = *(const float4*)(emb + (size_t)code * NC + k);
        int w = 0;
        w = __builtin_amdgcn_cvt_pk_fp8_f32(v.x * ESCALE, v.y * ESCALE, w, false);
        w = __builtin_amdgcn_cvt_pk_fp8_f32(v.z * ESCALE, v.w * ESCALE, w, true);
        *(int*)(packed + base) = w;
    } else {
        const int k = (blk - 256) * 256 + tid;    // 0..1023
        const float4* row = (const float4*)(emb + (size_t)k * NC);
        float s = 0.f;
#pragma unroll
        for (int i = 0; i < NC / 4; ++i) {
            float4 v = row[i];
            s = fmaf(v.x, v.x, fmaf(v.y, v.y, fmaf(v.z, v.z, fmaf(v.w, v.w, s))));
        }
        enorm2[k] = -256.0f * s;                  // = -||e_scaled||^2 / 2
    }
}

#define MX(A, B, C) __builtin_amdgcn_mfma_scale_f32_16x16x128_f8f6f4((A), (B), (C), 0, 0, 0, SC1, 0, SC1)

#define TAIL(MT, A, CH)                                                              \
    _Pragma("unroll")                                                                \
    for (int q = 0; q < 4; ++q) {                                                    \
        unsigned u = (__builtin_bit_cast(unsigned, (A)[q]) & 0xFFFFFFF0u) | (unsigned)(CH); \
        bestv[MT][q] = fmaxf(bestv[MT][q], __builtin_bit_cast(float, u));            \
    }

// one 64-code chunk. Latency-reordered: next-chunk loads issue right after the
// cluster that last reads the register they overwrite (~240-340 cyc cover)
#define KSTEP(CH, PF) do {                                                           \
    f32x4 a0 = {en, en, en, en}, a1 = a0, a2 = a0, a3 = a0;                          \
    __builtin_amdgcn_s_setprio(1);                                                   \
    a0 = MX(af[0][0], bA, a0); a1 = MX(af[1][0], bA, a1);                            \
    a2 = MX(af[2][0], bA, a2); a3 = MX(af[3][0], bA, a3);                            \
    __builtin_amdgcn_s_setprio(0);                                                   \
    if (PF) { bA = *(const i32x8*)(gpb + ((CH) + 1) * CH_BYTES);                     \
              en = enp[(((CH) + 1) << 6)]; }                                         \
    __builtin_amdgcn_s_setprio(1);                                                   \
    a0 = MX(af[0][1], bB, a0); a1 = MX(af[1][1], bB, a1);                            \
    a2 = MX(af[2][1], bB, a2); a3 = MX(af[3][1], bB, a3);                            \
    __builtin_amdgcn_s_setprio(0);                                                   \
    if (PF) { bB = *(const i32x8*)(gpb + ((CH) + 1) * CH_BYTES + 2048); }            \
    TAIL(0, a0, CH); TAIL(1, a1, CH); TAIL(2, a2, CH); TAIL(3, a3, CH);              \
} while (0)

// ---------- kernel A: distances + argmin (256 thr = 4 cg-waves over same 64 rows) ----------
__global__ __launch_bounds__(256, 4)
void vq_dist(const float* __restrict__ x, const unsigned char* __restrict__ packed,
             const float* __restrict__ enorm2, unsigned short* __restrict__ widx_g,
             float* __restrict__ partials)
{
    __shared__ __align__(16) char LDS[21536];
    char*  Xb   = LDS;                       // [64 r][256 B] fp8 XOR-swz, 16 KiB
    float* enl2 = (float*)(LDS + 16384);     // [1024]
    float* redv = (float*)(LDS + 20480);     // [4][64] packed floats
    float* wsum = (float*)(LDS + 21504);     // [4]

    const int tid  = threadIdx.x;
    const int blk  = blockIdx.x;
    const int b    = blk >> 6;
    const int hw0  = (blk & 63) << 6;
    const int cg   = tid >> 6;                 // wave = 16-code group
    const int lane = tid & 63;
    const int col  = lane & 15;
    const int g    = lane >> 4;

    // ---- stage x -> Xb[r][c] fp8 (scale 1), XOR-swizzled; + sum x^2 (fp32) ----
    float xsq = 0.f;
#pragma unroll
    for (int it = 0; it < 2; ++it) {
        const int r4 = (tid & 15) << 2;
        const int c0 = (((tid >> 4) & 15) + (it << 4)) << 3;
        float4 va[8];
#pragma unroll
        for (int cq = 0; cq < 8; ++cq) {
            va[cq] = *(const float4*)(x + (size_t)(b * NC + c0 + cq) * NHW + hw0 + r4);
            xsq = fmaf(va[cq].x, va[cq].x, fmaf(va[cq].y, va[cq].y,
                  fmaf(va[cq].z, va[cq].z, fmaf(va[cq].w, va[cq].w, xsq))));
        }
#pragma unroll
        for (int q = 0; q < 4; ++q) {
            const int r = r4 + q;
            int w0 = 0, w1 = 0;
            w0 = __builtin_amdgcn_cvt_pk_fp8_f32(((const float*)&va[0])[q], ((const float*)&va[1])[q], w0, false);
            w0 = __builtin_amdgcn_cvt_pk_fp8_f32(((const float*)&va[2])[q], ((const float*)&va[3])[q], w0, true);
            w1 = __builtin_amdgcn_cvt_pk_fp8_f32(((const float*)&va[4])[q], ((const float*)&va[5])[q], w1, false);
            w1 = __builtin_amdgcn_cvt_pk_fp8_f32(((const float*)&va[6])[q], ((const float*)&va[7])[q], w1, true);
            int2 wp = {w0, w1};
            *(int2*)(Xb + r * 256 + (c0 ^ ((r & 15) << 4))) = wp;
        }
    }
    *(float4*)&enl2[tid << 2] = *(const float4*)&enorm2[tid << 2];
#pragma unroll
    for (int o = 32; o > 0; o >>= 1) xsq += __shfl_down(xsq, o, 64);
    if (lane == 0) wsum[cg] = xsq;
    __syncthreads();

    // ---- A fragments: af[mt][h] = rows mt*16+col, k = h*128 + g*32 + (0..31) ----
    i32x8 af[4][2];
#pragma unroll
    for (int mt = 0; mt < 4; ++mt) {
        const int r = (mt << 4) + col;
#pragma unroll
        for (int h = 0; h < 2; ++h) {
            const int off = (h << 7) + (g << 5);
            const i32x4 lo = *(const i32x4*)(Xb + r * 256 + ((off)      ^ (col << 4)));
            const i32x4 hi = *(const i32x4*)(Xb + r * 256 + ((off + 16) ^ (col << 4)));
            af[mt][h] = __builtin_shufflevector(lo, hi, 0, 1, 2, 3, 4, 5, 6, 7);
        }
    }

    float bestv[4][4];
#pragma unroll
    for (int mt = 0; mt < 4; ++mt)
#pragma unroll
        for (int q = 0; q < 4; ++q) bestv[mt][q] = -3.4e38f;   // maximize 512*x.e - 256||e||^2

    // ---- K-loop: K=128 MX MFMA, latency-reordered prefetch, no barriers ----
    const char*  gpb = (const char*)packed + (cg << 12) + (lane << 5);   // 32 B/lane
    const float* enp = enl2 + (cg << 4) + col;
    i32x8 bA, bB;
    bA = *(const i32x8*)(gpb);
    bB = *(const i32x8*)(gpb + 2048);
    float en = enp[0];

#pragma unroll 1
    for (int ch = 0; ch < NCHUNK - 1; ++ch) KSTEP(ch, 1);
    KSTEP(NCHUNK - 1, 0);

    // ---- rebuild 10-bit code id in low mantissa bits ----
#pragma unroll
    for (int mt = 0; mt < 4; ++mt)
#pragma unroll
        for (int q = 0; q < 4; ++q) {
            unsigned u = __builtin_bit_cast(unsigned, bestv[mt][q]);
            const unsigned id = ((u & 15u) << 6) | ((unsigned)cg << 4) | (unsigned)col;
            u = (u & 0xFFFFFC00u) | id;
            bestv[mt][q] = __builtin_bit_cast(float, u);
        }

    // ---- cross-lane argmax over the 16 col-lanes (id travels inside float) ----
#pragma unroll
    for (int m = 1; m <= 8; m <<= 1)
#pragma unroll
        for (int mt = 0; mt < 4; ++mt)
#pragma unroll
            for (int q = 0; q < 4; ++q)
                bestv[mt][q] = fmaxf(bestv[mt][q], __shfl_xor(bestv[mt][q], m, 64));

    // ---- cross-wave (cg) argmax + widx + loss partial ----
    if (col == 0) {
#pragma unroll
        for (int mt = 0; mt < 4; ++mt)
#pragma unroll
            for (int q = 0; q < 4; ++q)
                redv[(cg << 6) + (mt << 4) + (g << 2) + q] = bestv[mt][q];
    }
    __syncthreads();
    if (tid < 64) {
        float w = fmaxf(fmaxf(redv[tid], redv[64 + tid]), fmaxf(redv[128 + tid], redv[192 + tid]));
        const unsigned u = __builtin_bit_cast(unsigned, w);
        widx_g[blk * 64 + tid] = (unsigned short)(u & 1023u);
        // true min-dist part: ||e||^2 - 2 x.e = -val/256
        const float val = __builtin_bit_cast(float, u & 0xFFFFFC00u);
        float bsum = val * (-1.0f / 256.0f);
#pragma unroll
        for (int o = 32; o > 0; o >>= 1) bsum += __shfl_down(bsum, o, 64);
        if (tid == 0)
            partials[blk] = bsum + wsum[0] + wsum[1] + wsum[2] + wsum[3];  // + sum x^2
    }
}

// ---------- kernel B: gather + transposed coalesced write (round-11 verbatim) ----------
__global__ __launch_bounds__(512, 2)
void vq_scatter(const float* __restrict__ emb, const unsigned short* __restrict__ widx_g,
                float* __restrict__ out)
{
    __shared__ __align__(16) char LDS[66304];
    float* Qt   = (float*)LDS;               // [64][258]
    int*   widx = (int*)(LDS + 66048);       // [64]

    const int tid  = threadIdx.x;
    const int blk  = blockIdx.x;
    const int b    = blk >> 6;
    const int hw0  = (blk & 63) << 6;
    const int wv   = tid >> 6;
    const int lane = tid & 63;

    if (tid < 64) widx[tid] = (int)widx_g[blk * 64 + tid];
    __syncthreads();

#pragma unroll
    for (int rr = 0; rr < 8; ++rr) {
        const int r  = (wv << 3) + rr;
        const int ki = widx[r];                         // wave-uniform broadcast
        const float4 ev = *(const float4*)(emb + (size_t)ki * NC + (lane << 2));
        float* qp = &Qt[r * QTS + (lane << 2)];
        *(float2*)qp       = {ev.x, ev.y};
        *(float2*)(qp + 2) = {ev.z, ev.w};
    }
    __syncthreads();
#pragma unroll 8
    for (int cc = 0; cc < 32; ++cc) {
        const int c = (wv << 5) + cc;
        out[(size_t)(b * NC + c) * NHW + hw0 + lane] = Qt[lane * QTS + c];
    }
}

// ---------- final loss reduction (separate tiny kernel — no device-scope fence) ----------
__global__ void vq_loss_final(const float* __restrict__ partials, float* __restrict__ out_loss) {
    __shared__ float sdata[256];
    float s = 0.f;
    for (int i = threadIdx.x; i < NTILES; i += 256) s += partials[i];
    sdata[threadIdx.x] = s;
    __syncthreads();
    for (int off = 128; off > 0; off >>= 1) {
        if (threadIdx.x < off) sdata[threadIdx.x] += sdata[threadIdx.x + off];
        __syncthreads();
    }
    if (threadIdx.x == 0)
        out_loss[0] = 1.25f * sdata[0] / (float)NUMEL;
}

extern "C" void kernel_launch(void* const* d_in, const int* in_sizes, int n_in,
                              void* d_out, int out_size, void* d_ws, size_t ws_size,
                              hipStream_t stream) {
    const float* x   = (const float*)d_in[0];
    const float* emb = (const float*)d_in[1];
    float* out = (float*)d_out;                              // [NUMEL] quantized + [1] loss
    char*  ws  = (char*)d_ws;
    float* partials = (float*)ws;                            // 2048 floats           @ 0
    float* enorm2   = (float*)(ws + 12288);                  // 1024 floats           @ 12K
    unsigned char*  packed = (unsigned char*)(ws + 16384);   // 256 KiB fp8 packed    @ 16K
    unsigned short* widx   = (unsigned short*)(ws + 278528); // 256 KiB indices

    hipLaunchKernelGGL(vq_prep, dim3(260), dim3(256), 0, stream, emb, packed, enorm2);
    hipLaunchKernelGGL(vq_dist, dim3(NTILES), dim3(256), 0, stream, x, packed, enorm2, widx, partials);
    hipLaunchKernelGGL(vq_scatter, dim3(NTILES), dim3(512), 0, stream, emb, widx, out);
    hipLaunchKernelGGL(vq_loss_final, dim3(1), dim3(256), 0, stream, partials, out + NUMEL);
}

// Round 14
// 92.302 us; speedup vs baseline: 2.0973x; 1.3108x over previous
//
#include <hip/hip_runtime.h>

typedef float  f32x4  __attribute__((ext_vector_type(4)));
typedef int    i32x4  __attribute__((ext_vector_type(4)));
typedef int    i32x8  __attribute__((ext_vector_type(8)));

#define NB 32
#define NC 256
#define NHW 4096                  // 64*64
#define NN (NB*NHW)               // 131072 rows
#define NK 1024                   // codes
#define NUMEL ((size_t)NN*NC)     // 33554432
#define BM 64                     // rows per block
#define NTILES (NN/BM)            // 2048 blocks
#define NCHUNK 16                 // 64 codes per chunk
#define CH_BYTES 16384            // 64 codes * 256 k * 1B
#define QTS 258                   // Qt row stride (floats)
#define ESCALE 512.0f             // emb scaled by 512 before fp8 quant
#define SC1 0x7F7F7F7F            // E8M0 scale = 1.0 in all byte slots

// ---------- prep: prepack emb -> fp8 fragments + enorm2 (merged, 1 launch) ----------
// packed byte off bits: [ch 4][cg 2][h 1][g 2][col 4][kk 5]
// code = ch*64 + cg*16 + col ; k = h*128 + g*32 + kk
__global__ void vq_prep(const float* __restrict__ emb, unsigned char* __restrict__ packed,
                        float* __restrict__ enorm2) {
    const int blk = blockIdx.x;
    const int tid = threadIdx.x;
    if (blk < 256) {
        const int base = (blk * 256 + tid) * 4;   // 4 bytes/thread, same k-quad
        const int kk0 = base & 31;
        const int col = (base >> 5) & 15;
        const int g   = (base >> 9) & 3;
        const int h   = (base >> 11) & 1;
        const int cg  = (base >> 12) & 3;
        const int ch  = base >> 14;
        const int code = ch * 64 + cg * 16 + col;
        const int k    = h * 128 + g * 32 + kk0;
        const float4 v = *(const float4*)(emb + (size_t)code * NC + k);
        int w = 0;
        w = __builtin_amdgcn_cvt_pk_fp8_f32(v.x * ESCALE, v.y * ESCALE, w, false);
        w = __builtin_amdgcn_cvt_pk_fp8_f32(v.z * ESCALE, v.w * ESCALE, w, true);
        *(int*)(packed + base) = w;
    } else {
        const int k = (blk - 256) * 256 + tid;    // 0..1023
        const float4* row = (const float4*)(emb + (size_t)k * NC);
        float s = 0.f;
#pragma unroll
        for (int i = 0; i < NC / 4; ++i) {
            float4 v = row[i];
            s = fmaf(v.x, v.x, fmaf(v.y, v.y, fmaf(v.z, v.z, fmaf(v.w, v.w, s))));
        }
        enorm2[k] = -256.0f * s;                  // = -||e_scaled||^2 / 2
    }
}

#define MX(A, B, C) __builtin_amdgcn_mfma_scale_f32_16x16x128_f8f6f4((A), (B), (C), 0, 0, 0, SC1, 0, SC1)

#define TAIL(MT, A, CH)                                                              \
    _Pragma("unroll")                                                                \
    for (int q = 0; q < 4; ++q) {                                                    \
        unsigned u = (__builtin_bit_cast(unsigned, (A)[q]) & 0xFFFFFFF0u) | (unsigned)(CH); \
        bestv[MT][q] = fmaxf(bestv[MT][q], __builtin_bit_cast(float, u));            \
    }

// one 64-code chunk — ROUND-11 SCHEDULE, FROZEN (any live-range extension spills)
#define KSTEP(CH) do {                                                               \
    bB = *(const i32x8*)(gpb + (CH) * CH_BYTES + 2048);                              \
    const float en_ = enl2[((CH) << 6) + (cg << 4) + col];                           \
    f32x4 a0 = {en_, en_, en_, en_}, a1 = a0, a2 = a0, a3 = a0;                      \
    __builtin_amdgcn_s_setprio(1);                                                   \
    a0 = MX(af[0][0], bA, a0); a1 = MX(af[1][0], bA, a1);                            \
    a2 = MX(af[2][0], bA, a2); a3 = MX(af[3][0], bA, a3);                            \
    __builtin_amdgcn_s_setprio(0);                                                   \
    const int chn_ = ((CH) < NCHUNK - 1) ? (CH) + 1 : (CH);                          \
    bA = *(const i32x8*)(gpb + chn_ * CH_BYTES);                                     \
    __builtin_amdgcn_s_setprio(1);                                                   \
    a0 = MX(af[0][1], bB, a0); a1 = MX(af[1][1], bB, a1);                            \
    a2 = MX(af[2][1], bB, a2); a3 = MX(af[3][1], bB, a3);                            \
    __builtin_amdgcn_s_setprio(0);                                                   \
    TAIL(0, a0, CH); TAIL(1, a1, CH); TAIL(2, a2, CH); TAIL(3, a3, CH);              \
} while (0)

// ---------- kernel A: distances + argmin (256 thr = 4 cg-waves over same 64 rows) ----------
__global__ __launch_bounds__(256, 4)
void vq_dist(const float* __restrict__ x, const unsigned char* __restrict__ packed,
             const float* __restrict__ enorm2, unsigned short* __restrict__ widx_g,
             float* __restrict__ partials)
{
    __shared__ __align__(16) char LDS[21536];
    char*  Xb   = LDS;                       // [64 r][256 B] fp8 XOR-swz, 16 KiB
    float* enl2 = (float*)(LDS + 16384);     // [1024]
    float* redv = (float*)(LDS + 20480);     // [4][64] packed floats
    float* wsum = (float*)(LDS + 21504);     // [4]

    const int tid  = threadIdx.x;
    const int blk  = blockIdx.x;
    const int b    = blk >> 6;
    const int hw0  = (blk & 63) << 6;
    const int cg   = tid >> 6;                 // wave = 16-code group
    const int lane = tid & 63;
    const int col  = lane & 15;
    const int g    = lane >> 4;

    // ---- stage x -> Xb[r][c] fp8 (scale 1), XOR-swizzled; + sum x^2 (fp32) ----
    float xsq = 0.f;
#pragma unroll
    for (int it = 0; it < 2; ++it) {
        const int r4 = (tid & 15) << 2;
        const int c0 = (((tid >> 4) & 15) + (it << 4)) << 3;
        float4 va[8];
#pragma unroll
        for (int cq = 0; cq < 8; ++cq) {
            va[cq] = *(const float4*)(x + (size_t)(b * NC + c0 + cq) * NHW + hw0 + r4);
            xsq = fmaf(va[cq].x, va[cq].x, fmaf(va[cq].y, va[cq].y,
                  fmaf(va[cq].z, va[cq].z, fmaf(va[cq].w, va[cq].w, xsq))));
        }
#pragma unroll
        for (int q = 0; q < 4; ++q) {
            const int r = r4 + q;
            int w0 = 0, w1 = 0;
            w0 = __builtin_amdgcn_cvt_pk_fp8_f32(((const float*)&va[0])[q], ((const float*)&va[1])[q], w0, false);
            w0 = __builtin_amdgcn_cvt_pk_fp8_f32(((const float*)&va[2])[q], ((const float*)&va[3])[q], w0, true);
            w1 = __builtin_amdgcn_cvt_pk_fp8_f32(((const float*)&va[4])[q], ((const float*)&va[5])[q], w1, false);
            w1 = __builtin_amdgcn_cvt_pk_fp8_f32(((const float*)&va[6])[q], ((const float*)&va[7])[q], w1, true);
            int2 wp = {w0, w1};
            *(int2*)(Xb + r * 256 + (c0 ^ ((r & 15) << 4))) = wp;
        }
    }
    *(float4*)&enl2[tid << 2] = *(const float4*)&enorm2[tid << 2];
#pragma unroll
    for (int o = 32; o > 0; o >>= 1) xsq += __shfl_down(xsq, o, 64);
    if (lane == 0) wsum[cg] = xsq;
    __syncthreads();

    // ---- A fragments: af[mt][h] = rows mt*16+col, k = h*128 + g*32 + (0..31) ----
    i32x8 af[4][2];
#pragma unroll
    for (int mt = 0; mt < 4; ++mt) {
        const int r = (mt << 4) + col;
#pragma unroll
        for (int h = 0; h < 2; ++h) {
            const int off = (h << 7) + (g << 5);
            const i32x4 lo = *(const i32x4*)(Xb + r * 256 + ((off)      ^ (col << 4)));
            const i32x4 hi = *(const i32x4*)(Xb + r * 256 + ((off + 16) ^ (col << 4)));
            af[mt][h] = __builtin_shufflevector(lo, hi, 0, 1, 2, 3, 4, 5, 6, 7);
        }
    }

    float bestv[4][4];
#pragma unroll
    for (int mt = 0; mt < 4; ++mt)
#pragma unroll
        for (int q = 0; q < 4; ++q) bestv[mt][q] = -3.4e38f;   // maximize 512*x.e - 256||e||^2

    // ---- K-loop: K=128 MX MFMA, B ping-pong (bA/bB, 16 regs), no barriers ----
    const char* gpb = (const char*)packed + (cg << 12) + (lane << 5);   // 32 B/lane
    i32x8 bA, bB;
    bA = *(const i32x8*)(gpb);

#pragma unroll 1
    for (int ch = 0; ch < NCHUNK; ++ch) KSTEP(ch);

    // ---- rebuild 10-bit code id in low mantissa bits ----
#pragma unroll
    for (int mt = 0; mt < 4; ++mt)
#pragma unroll
        for (int q = 0; q < 4; ++q) {
            unsigned u = __builtin_bit_cast(unsigned, bestv[mt][q]);
            const unsigned id = ((u & 15u) << 6) | ((unsigned)cg << 4) | (unsigned)col;
            u = (u & 0xFFFFFC00u) | id;
            bestv[mt][q] = __builtin_bit_cast(float, u);
        }

    // ---- cross-lane argmax over the 16 col-lanes (id travels inside float) ----
#pragma unroll
    for (int m = 1; m <= 8; m <<= 1)
#pragma unroll
        for (int mt = 0; mt < 4; ++mt)
#pragma unroll
            for (int q = 0; q < 4; ++q)
                bestv[mt][q] = fmaxf(bestv[mt][q], __shfl_xor(bestv[mt][q], m, 64));

    // ---- cross-wave (cg) argmax + widx + loss partial ----
    if (col == 0) {
#pragma unroll
        for (int mt = 0; mt < 4; ++mt)
#pragma unroll
            for (int q = 0; q < 4; ++q)
                redv[(cg << 6) + (mt << 4) + (g << 2) + q] = bestv[mt][q];
    }
    __syncthreads();
    if (tid < 64) {
        float w = fmaxf(fmaxf(redv[tid], redv[64 + tid]), fmaxf(redv[128 + tid], redv[192 + tid]));
        const unsigned u = __builtin_bit_cast(unsigned, w);
        widx_g[blk * 64 + tid] = (unsigned short)(u & 1023u);
        // true min-dist part: ||e||^2 - 2 x.e = -val/256
        const float val = __builtin_bit_cast(float, u & 0xFFFFFC00u);
        float bsum = val * (-1.0f / 256.0f);
#pragma unroll
        for (int o = 32; o > 0; o >>= 1) bsum += __shfl_down(bsum, o, 64);
        if (tid == 0)
            partials[blk] = bsum + wsum[0] + wsum[1] + wsum[2] + wsum[3];  // + sum x^2
    }
}

// ---------- kernel B: gather + transposed coalesced write (round-11 verbatim) ----------
__global__ __launch_bounds__(512, 2)
void vq_scatter(const float* __restrict__ emb, const unsigned short* __restrict__ widx_g,
                float* __restrict__ out)
{
    __shared__ __align__(16) char LDS[66304];
    float* Qt   = (float*)LDS;               // [64][258]
    int*   widx = (int*)(LDS + 66048);       // [64]

    const int tid  = threadIdx.x;
    const int blk  = blockIdx.x;
    const int b    = blk >> 6;
    const int hw0  = (blk & 63) << 6;
    const int wv   = tid >> 6;
    const int lane = tid & 63;

    if (tid < 64) widx[tid] = (int)widx_g[blk * 64 + tid];
    __syncthreads();

#pragma unroll
    for (int rr = 0; rr < 8; ++rr) {
        const int r  = (wv << 3) + rr;
        const int ki = widx[r];                         // wave-uniform broadcast
        const float4 ev = *(const float4*)(emb + (size_t)ki * NC + (lane << 2));
        float* qp = &Qt[r * QTS + (lane << 2)];
        *(float2*)qp       = {ev.x, ev.y};
        *(float2*)(qp + 2) = {ev.z, ev.w};
    }
    __syncthreads();
#pragma unroll 8
    for (int cc = 0; cc < 32; ++cc) {
        const int c = (wv << 5) + cc;
        out[(size_t)(b * NC + c) * NHW + hw0 + lane] = Qt[lane * QTS + c];
    }
}

// ---------- final loss reduction (separate tiny kernel — no device-scope fence) ----------
__global__ void vq_loss_final(const float* __restrict__ partials, float* __restrict__ out_loss) {
    __shared__ float sdata[256];
    float s = 0.f;
    for (int i = threadIdx.x; i < NTILES; i += 256) s += partials[i];
    sdata[threadIdx.x] = s;
    __syncthreads();
    for (int off = 128; off > 0; off >>= 1) {
        if (threadIdx.x < off) sdata[threadIdx.x] += sdata[threadIdx.x + off];
        __syncthreads();
    }
    if (threadIdx.x == 0)
        out_loss[0] = 1.25f * sdata[0] / (float)NUMEL;
}

extern "C" void kernel_launch(void* const* d_in, const int* in_sizes, int n_in,
                              void* d_out, int out_size, void* d_ws, size_t ws_size,
                              hipStream_t stream) {
    const float* x   = (const float*)d_in[0];
    const float* emb = (const float*)d_in[1];
    float* out = (float*)d_out;                              // [NUMEL] quantized + [1] loss
    char*  ws  = (char*)d_ws;
    float* partials = (float*)ws;                            // 2048 floats           @ 0
    float* enorm2   = (float*)(ws + 12288);                  // 1024 floats           @ 12K
    unsigned char*  packed = (unsigned char*)(ws + 16384);   // 256 KiB fp8 packed    @ 16K
    unsigned short* widx   = (unsigned short*)(ws + 278528); // 256 KiB indices

    hipLaunchKernelGGL(vq_prep, dim3(260), dim3(256), 0, stream, emb, packed, enorm2);
    hipLaunchKernelGGL(vq_dist, dim3(NTILES), dim3(256), 0, stream, x, packed, enorm2, widx, partials);
    hipLaunchKernelGGL(vq_scatter, dim3(NTILES), dim3(512), 0, stream, emb, widx, out);
    hipLaunchKernelGGL(vq_loss_final, dim3(1), dim3(256), 0, stream, partials, out + NUMEL);
}

// Round 15
// 87.548 us; speedup vs baseline: 2.2112x; 1.0543x over previous
//
#include <hip/hip_runtime.h>

typedef float  f32x4  __attribute__((ext_vector_type(4)));
typedef int    i32x4  __attribute__((ext_vector_type(4)));
typedef int    i32x8  __attribute__((ext_vector_type(8)));

#define NB 32
#define NC 256
#define NHW 4096                  // 64*64
#define NN (NB*NHW)               // 131072 rows
#define NK 1024                   // codes
#define NUMEL ((size_t)NN*NC)     // 33554432
#define BM 64                     // rows per block
#define NTILES (NN/BM)            // 2048 blocks
#define NCHUNK 16                 // 64 codes per chunk
#define CH_BYTES 16384            // 64 codes * 256 k * 1B
#define QTS 258                   // Qt row stride (floats)
#define ESCALE 512.0f             // emb scaled by 512 before fp8 quant
#define SC1 0x7F7F7F7F            // E8M0 scale = 1.0 in all byte slots

// ---------- prep: prepack emb -> fp8 fragments + enorm2 (merged, 1 launch) ----------
// packed byte off bits: [ch 4][cg 2][h 1][g 2][col 4][kk 5]
// code = ch*64 + cg*16 + col ; k = h*128 + g*32 + kk
__global__ void vq_prep(const float* __restrict__ emb, unsigned char* __restrict__ packed,
                        float* __restrict__ enorm2) {
    const int blk = blockIdx.x;
    const int tid = threadIdx.x;
    if (blk < 256) {
        const int base = (blk * 256 + tid) * 4;   // 4 bytes/thread, same k-quad
        const int kk0 = base & 31;
        const int col = (base >> 5) & 15;
        const int g   = (base >> 9) & 3;
        const int h   = (base >> 11) & 1;
        const int cg  = (base >> 12) & 3;
        const int ch  = base >> 14;
        const int code = ch * 64 + cg * 16 + col;
        const int k    = h * 128 + g * 32 + kk0;
        const float4 v = *(const float4*)(emb + (size_t)code * NC + k);
        int w = 0;
        w = __builtin_amdgcn_cvt_pk_fp8_f32(v.x * ESCALE, v.y * ESCALE, w, false);
        w = __builtin_amdgcn_cvt_pk_fp8_f32(v.z * ESCALE, v.w * ESCALE, w, true);
        *(int*)(packed + base) = w;
    } else {
        const int k = (blk - 256) * 256 + tid;    // 0..1023
        const float4* row = (const float4*)(emb + (size_t)k * NC);
        float s = 0.f;
#pragma unroll
        for (int i = 0; i < NC / 4; ++i) {
            float4 v = row[i];
            s = fmaf(v.x, v.x, fmaf(v.y, v.y, fmaf(v.z, v.z, fmaf(v.w, v.w, s))));
        }
        enorm2[k] = -256.0f * s;                  // = -||e_scaled||^2 / 2
    }
}

#define MX(A, B, C) __builtin_amdgcn_mfma_scale_f32_16x16x128_f8f6f4((A), (B), (C), 0, 0, 0, SC1, 0, SC1)

#define TAIL(MT, A, CH)                                                              \
    _Pragma("unroll")                                                                \
    for (int q = 0; q < 4; ++q) {                                                    \
        unsigned u = (__builtin_bit_cast(unsigned, (A)[q]) & 0xFFFFFFF0u) | (unsigned)(CH); \
        bestv[MT][q] = fmaxf(bestv[MT][q], __builtin_bit_cast(float, u));            \
    }

// one 64-code chunk — ROUND-11 SCHEDULE, FROZEN (any live-range extension spills)
#define KSTEP(CH) do {                                                               \
    bB = *(const i32x8*)(gpb + (CH) * CH_BYTES + 2048);                              \
    const float en_ = enl2[((CH) << 6) + (cg << 4) + col];                           \
    f32x4 a0 = {en_, en_, en_, en_}, a1 = a0, a2 = a0, a3 = a0;                      \
    __builtin_amdgcn_s_setprio(1);                                                   \
    a0 = MX(af[0][0], bA, a0); a1 = MX(af[1][0], bA, a1);                            \
    a2 = MX(af[2][0], bA, a2); a3 = MX(af[3][0], bA, a3);                            \
    __builtin_amdgcn_s_setprio(0);                                                   \
    const int chn_ = ((CH) < NCHUNK - 1) ? (CH) + 1 : (CH);                          \
    bA = *(const i32x8*)(gpb + chn_ * CH_BYTES);                                     \
    __builtin_amdgcn_s_setprio(1);                                                   \
    a0 = MX(af[0][1], bB, a0); a1 = MX(af[1][1], bB, a1);                            \
    a2 = MX(af[2][1], bB, a2); a3 = MX(af[3][1], bB, a3);                            \
    __builtin_amdgcn_s_setprio(0);                                                   \
    TAIL(0, a0, CH); TAIL(1, a1, CH); TAIL(2, a2, CH); TAIL(3, a3, CH);              \
} while (0)

// ---------- kernel A: distances + argmin (256 thr = 4 cg-waves over same 64 rows) ----------
__global__ __launch_bounds__(256, 4)
void vq_dist(const float* __restrict__ x, const unsigned char* __restrict__ packed,
             const float* __restrict__ enorm2, unsigned short* __restrict__ widx_g,
             float* __restrict__ partials)
{
    __shared__ __align__(16) char LDS[21536];
    char*  Xb   = LDS;                       // [64 r][256 B] fp8 XOR-swz, 16 KiB
    float* enl2 = (float*)(LDS + 16384);     // [1024]
    float* redv = (float*)(LDS + 20480);     // [4][64] packed floats
    float* wsum = (float*)(LDS + 21504);     // [4]

    const int tid  = threadIdx.x;
    const int blk  = blockIdx.x;
    const int b    = blk >> 6;
    const int hw0  = (blk & 63) << 6;
    const int cg   = tid >> 6;                 // wave = 16-code group
    const int lane = tid & 63;
    const int col  = lane & 15;
    const int g    = lane >> 4;

    // chunk-0 bA: issue before staging — L2-cold latency hides under the stage phase.
    // (+16 regs live through staging where pressure ~70 << K-loop peak: no alloc impact)
    const char* gpb = (const char*)packed + (cg << 12) + (lane << 5);   // 32 B/lane
    i32x8 bA, bB;
    bA = *(const i32x8*)(gpb);

    // ---- stage x -> Xb[r][c] fp8 (scale 1), XOR-swizzled; + sum x^2 (fp32) ----
    float xsq = 0.f;
#pragma unroll
    for (int it = 0; it < 2; ++it) {
        const int r4 = (tid & 15) << 2;
        const int c0 = (((tid >> 4) & 15) + (it << 4)) << 3;
        float4 va[8];
#pragma unroll
        for (int cq = 0; cq < 8; ++cq) {
            va[cq] = *(const float4*)(x + (size_t)(b * NC + c0 + cq) * NHW + hw0 + r4);
            xsq = fmaf(va[cq].x, va[cq].x, fmaf(va[cq].y, va[cq].y,
                  fmaf(va[cq].z, va[cq].z, fmaf(va[cq].w, va[cq].w, xsq))));
        }
#pragma unroll
        for (int q = 0; q < 4; ++q) {
            const int r = r4 + q;
            int w0 = 0, w1 = 0;
            w0 = __builtin_amdgcn_cvt_pk_fp8_f32(((const float*)&va[0])[q], ((const float*)&va[1])[q], w0, false);
            w0 = __builtin_amdgcn_cvt_pk_fp8_f32(((const float*)&va[2])[q], ((const float*)&va[3])[q], w0, true);
            w1 = __builtin_amdgcn_cvt_pk_fp8_f32(((const float*)&va[4])[q], ((const float*)&va[5])[q], w1, false);
            w1 = __builtin_amdgcn_cvt_pk_fp8_f32(((const float*)&va[6])[q], ((const float*)&va[7])[q], w1, true);
            int2 wp = {w0, w1};
            *(int2*)(Xb + r * 256 + (c0 ^ ((r & 15) << 4))) = wp;
        }
    }
    *(float4*)&enl2[tid << 2] = *(const float4*)&enorm2[tid << 2];
#pragma unroll
    for (int o = 32; o > 0; o >>= 1) xsq += __shfl_down(xsq, o, 64);
    if (lane == 0) wsum[cg] = xsq;
    __syncthreads();

    // ---- A fragments: af[mt][h] = rows mt*16+col, k = h*128 + g*32 + (0..31) ----
    i32x8 af[4][2];
#pragma unroll
    for (int mt = 0; mt < 4; ++mt) {
        const int r = (mt << 4) + col;
#pragma unroll
        for (int h = 0; h < 2; ++h) {
            const int off = (h << 7) + (g << 5);
            const i32x4 lo = *(const i32x4*)(Xb + r * 256 + ((off)      ^ (col << 4)));
            const i32x4 hi = *(const i32x4*)(Xb + r * 256 + ((off + 16) ^ (col << 4)));
            af[mt][h] = __builtin_shufflevector(lo, hi, 0, 1, 2, 3, 4, 5, 6, 7);
        }
    }

    float bestv[4][4];
#pragma unroll
    for (int mt = 0; mt < 4; ++mt)
#pragma unroll
        for (int q = 0; q < 4; ++q) bestv[mt][q] = -3.4e38f;   // maximize 512*x.e - 256||e||^2

    // ---- K-loop: K=128 MX MFMA, B ping-pong (bA/bB, 16 regs), no barriers ----
#pragma unroll 1
    for (int ch = 0; ch < NCHUNK; ++ch) KSTEP(ch);

    // ---- rebuild 10-bit code id in low mantissa bits ----
#pragma unroll
    for (int mt = 0; mt < 4; ++mt)
#pragma unroll
        for (int q = 0; q < 4; ++q) {
            unsigned u = __builtin_bit_cast(unsigned, bestv[mt][q]);
            const unsigned id = ((u & 15u) << 6) | ((unsigned)cg << 4) | (unsigned)col;
            u = (u & 0xFFFFFC00u) | id;
            bestv[mt][q] = __builtin_bit_cast(float, u);
        }

    // ---- cross-lane argmax over the 16 col-lanes (id travels inside float) ----
#pragma unroll
    for (int m = 1; m <= 8; m <<= 1)
#pragma unroll
        for (int mt = 0; mt < 4; ++mt)
#pragma unroll
            for (int q = 0; q < 4; ++q)
                bestv[mt][q] = fmaxf(bestv[mt][q], __shfl_xor(bestv[mt][q], m, 64));

    // ---- cross-wave (cg) argmax + widx + loss partial ----
    if (col == 0) {
#pragma unroll
        for (int mt = 0; mt < 4; ++mt)
#pragma unroll
            for (int q = 0; q < 4; ++q)
                redv[(cg << 6) + (mt << 4) + (g << 2) + q] = bestv[mt][q];
    }
    __syncthreads();
    if (tid < 64) {
        float w = fmaxf(fmaxf(redv[tid], redv[64 + tid]), fmaxf(redv[128 + tid], redv[192 + tid]));
        const unsigned u = __builtin_bit_cast(unsigned, w);
        widx_g[blk * 64 + tid] = (unsigned short)(u & 1023u);
        // true min-dist part: ||e||^2 - 2 x.e = -val/256
        const float val = __builtin_bit_cast(float, u & 0xFFFFFC00u);
        float bsum = val * (-1.0f / 256.0f);
#pragma unroll
        for (int o = 32; o > 0; o >>= 1) bsum += __shfl_down(bsum, o, 64);
        if (tid == 0)
            partials[blk] = bsum + wsum[0] + wsum[1] + wsum[2] + wsum[3];  // + sum x^2
    }
}

// ---------- kernel B: gather + transposed write; block NTILES = loss-final ----------
// (loss fold is safe here: partials comes from the PREVIOUS kernel — coherent at
//  launch, no device-scope fence needed; round-12's fence bug was intra-kernel)
__global__ __launch_bounds__(512, 2)
void vq_scatter(const float* __restrict__ emb, const unsigned short* __restrict__ widx_g,
                float* __restrict__ out, const float* __restrict__ partials)
{
    __shared__ __align__(16) char LDS[66304];
    const int tid  = threadIdx.x;
    const int blk  = blockIdx.x;

    if (blk == NTILES) {   // loss-final block (deterministic fixed-order reduce)
        float* sdata = (float*)LDS;
        float s = 0.f;
        for (int i = tid; i < NTILES; i += 512) s += partials[i];
        sdata[tid] = s;
        __syncthreads();
        for (int off = 256; off > 0; off >>= 1) {
            if (tid < off) sdata[tid] += sdata[tid + off];
            __syncthreads();
        }
        if (tid == 0) out[NUMEL] = 1.25f * sdata[0] / (float)NUMEL;
        return;
    }

    float* Qt   = (float*)LDS;               // [64][258]
    int*   widx = (int*)(LDS + 66048);       // [64]
    const int b    = blk >> 6;
    const int hw0  = (blk & 63) << 6;
    const int wv   = tid >> 6;
    const int lane = tid & 63;

    if (tid < 64) widx[tid] = (int)widx_g[blk * 64 + tid];
    __syncthreads();

#pragma unroll
    for (int rr = 0; rr < 8; ++rr) {
        const int r  = (wv << 3) + rr;
        const int ki = widx[r];                         // wave-uniform broadcast
        const float4 ev = *(const float4*)(emb + (size_t)ki * NC + (lane << 2));
        float* qp = &Qt[r * QTS + (lane << 2)];
        *(float2*)qp       = {ev.x, ev.y};
        *(float2*)(qp + 2) = {ev.z, ev.w};
    }
    __syncthreads();
#pragma unroll 8
    for (int cc = 0; cc < 32; ++cc) {
        const int c = (wv << 5) + cc;
        out[(size_t)(b * NC + c) * NHW + hw0 + lane] = Qt[lane * QTS + c];
    }
}

extern "C" void kernel_launch(void* const* d_in, const int* in_sizes, int n_in,
                              void* d_out, int out_size, void* d_ws, size_t ws_size,
                              hipStream_t stream) {
    const float* x   = (const float*)d_in[0];
    const float* emb = (const float*)d_in[1];
    float* out = (float*)d_out;                              // [NUMEL] quantized + [1] loss
    char*  ws  = (char*)d_ws;
    float* partials = (float*)ws;                            // 2048 floats           @ 0
    float* enorm2   = (float*)(ws + 12288);                  // 1024 floats           @ 12K
    unsigned char*  packed = (unsigned char*)(ws + 16384);   // 256 KiB fp8 packed    @ 16K
    unsigned short* widx   = (unsigned short*)(ws + 278528); // 256 KiB indices

    hipLaunchKernelGGL(vq_prep, dim3(260), dim3(256), 0, stream, emb, packed, enorm2);
    hipLaunchKernelGGL(vq_dist, dim3(NTILES), dim3(256), 0, stream, x, packed, enorm2, widx, partials);
    hipLaunchKernelGGL(vq_scatter, dim3(NTILES + 1), dim3(512), 0, stream, emb, widx, out, partials);
}